// Round 6
// baseline (491.597 us; speedup 1.0000x reference)
//
#include <hip/hip_runtime.h>
#include <hip/hip_bf16.h>
#include <cstdint>
#include <cstddef>

typedef __bf16 bf16_t;
typedef __bf16 bf16x8 __attribute__((ext_vector_type(8)));
typedef float f32x4 __attribute__((ext_vector_type(4)));
typedef float f32x16 __attribute__((ext_vector_type(16)));

#define TOKENS 8192
#define IN_F 4096
#define OUT_F 4096

// fallback (128^2) geometry
#define BM 128
#define BN 128
#define BK 32

// 256^2 geometry
#define GK 64
#define NT (IN_F / GK)   // 64 K-tiles

// async global->LDS, 16B per lane; LDS dest is wave-uniform base + lane*16
#define GLDS(gp, lp)                                                      \
  __builtin_amdgcn_global_load_lds(                                       \
      (__attribute__((address_space(1))) void*)(gp),                      \
      (__attribute__((address_space(3))) void*)(lp), 16, 0, 0)

#define SB0() __builtin_amdgcn_sched_barrier(0)

// ---------------- dequant: packed nibbles -> bf16 W[OUT_F][IN_F] ----------
__global__ __launch_bounds__(256) void dequant_nf4(
    const int* __restrict__ qw, const int* __restrict__ am1,
    const float* __restrict__ cd1, const float* __restrict__ of1,
    const float* __restrict__ am2, const float* __restrict__ cd2,
    bf16_t* __restrict__ W) {
  const int t = blockIdx.x * 256 + threadIdx.x;
  const int e0 = t << 3;        // 8 dequantized elements per thread
  const int b1 = e0 >> 6;       // primary block (64 elems) -- all 8 share it
  const int b2 = e0 >> 8;       // secondary block (256 elems)
  const int4 v = *(const int4*)(qw + (t << 2));
  const float s2 = am2[b2] / cd2[b2];
  const float s1 = ((float)am1[b1] / cd1[b1]) * s2;
  const float off = of1[b1];
  int vv[4] = {v.x, v.y, v.z, v.w};
  bf16x8 w;
#pragma unroll
  for (int i = 0; i < 4; ++i) {
    w[2 * i]     = (bf16_t)(((float)(vv[i] & 15) - off) * s1);
    w[2 * i + 1] = (bf16_t)(((float)((vv[i] >> 4) & 15) - off) * s1);
  }
  *(bf16x8*)(W + e0) = w;
}

// ---------------- X: f32 -> bf16 one-shot convert -------------------------
__global__ __launch_bounds__(256) void conv_x(
    const float* __restrict__ X, bf16_t* __restrict__ Xb) {
  const size_t e0 = ((size_t)blockIdx.x * 256 + threadIdx.x) << 3;
  f32x4 a = *(const f32x4*)(X + e0);
  f32x4 b = *(const f32x4*)(X + e0 + 4);
  bf16x8 w;
#pragma unroll
  for (int i = 0; i < 4; ++i) {
    w[i] = (bf16_t)a[i];
    w[i + 4] = (bf16_t)b[i];
  }
  *(bf16x8*)(Xb + e0) = w;
}

// ======== GEMM: 256x256 tile, BK=64, 8-wave, 32x32x16 MFMA ================
// C[M,N] = Xb[M,K]*W[N,K]^T.  Round-6 change: MFMA shape 16x16x32 ->
// 32x32x16 (sustained 2382 vs 2075 TF; half the instructions). LDS layout,
// staging, barriers and the decoupled 8-sub-phase skeleton are unchanged
// from round 5 (verified passing).
//
// Fragment layouts (32x32x16 bf16):
//   A/B: lane l holds row/col = l&31, k = (l>>5)*8 + 0..7 (K-doubling of
//        the verified 32x32x8 layout; analog of our verified 16x16x32).
//   C/D: col = lane&31, row = (reg&3) + 8*(reg>>2) + 4*(lane>>5)  [m74/m101]
//
// Per tile t (buf b), wave tile 128x64 = 4x2 grid of 32x32, K=64 = 4 ksteps.
// Clusters c(p,k): 4 MFMA, p = row-pair (i=2p,2p+1), k = kstep.
//  s0: rd{A01k1,Bk1}    | c(0,0) | stageA(t+1,h0); vmcnt(6); barrier [P0]
//  s1: rd{A23k0}        | c(0,1)
//  s2: rd{A23k1}        | c(1,0) | stageA(t+1,h1)
//  s3: rd{A01k2,Bk2}    | c(1,1)
//  s4: rd{A01k3,Bk3}    | c(0,2)
//  s5: rd{A23k2}        | c(0,3) | vmcnt(2); barrier [P2]
//  s6: rd{A23k3}        | c(1,2) | stageB(t+2,h0)
//  s7: rd{A01k0',Bk0'}  | c(1,3) | stageB(t+2,h1)
// Hi-row A reads (s1,s2,s5,s6) all after P0's vmcnt(6) (drains A(t)h1).
// P2 vmcnt(2) drains B(t+1)+A(t+1)h0 (s7's reads), leaves A(t+1)h1 for the
// next P0. Wrap-staging keeps counts uniform; final vmcnt(0) drains.
__global__ __launch_bounds__(512) void gemm_8p(
    const bf16_t* __restrict__ X, const bf16_t* __restrict__ Wq,
    float* __restrict__ C) {
  __shared__ __align__(16) bf16_t smem[65536];   // 128 KiB
  bf16_t* const As = smem;            // 2 bufs x 32 KB
  bf16_t* const Bs = smem + 32768;

  const int tid  = threadIdx.x;
  const int l    = tid & 63;
  const int w    = tid >> 6;          // 8 waves
  const int wm   = w >> 2;            // 2 along M (128 rows each)
  const int wn   = w & 3;             // 4 along N (64 cols each)

  // T1: XCD-aware bijective swizzle (nwg=512, 512%8==0)
  const int swz = (blockIdx.x & 7) * 64 + (blockIdx.x >> 3);
  const int m0 = (swz >> 4) * 256;    // 32 m-tiles
  const int n0 = (swz & 15) * 256;    // 16 n-tiles

  // inverse st_16x32 swizzle on the global source column
  const int gcolA = ((l & 3) << 3) ^ ((l & 32) ? 16 : 0);
  const int gcolB = ((w & 1) << 5) + gcolA;   // col-half for B

  // ---- A staging: wave w -> wm=w>>2, R=4h+(w&3); 2 GLDS = Cb 0,1 ----
  const int awm = w >> 2;
  const int ar  = w & 3;
  const bf16_t* const gAs =
      X + (size_t)(m0 + awm * 128 + ar * 16 + (l >> 2)) * IN_F + gcolA;
  auto stageA = [&](int kt, int h) {
    const bf16_t* s = gAs + (size_t)(h * 64) * IN_F + kt * GK;
    bf16_t* d = As + ((kt & 1) << 14) +
                (((awm << 4) | (((h << 2) + ar) << 1)) << 9);
    GLDS(s, d);            // Cb=0
    GLDS(s + 32, d + 512); // Cb=1
  };

  // ---- B staging: wave w -> rows 16*(w>>1)+.. and +64 of col-half (w&1),
  //      row-half h; writes subtiles w and w+8 of buf's h-region ----
  const int grow = ((w >> 1) << 4) + (l >> 2);
  const bf16_t* const gB = Wq + (size_t)(n0 + grow) * IN_F + gcolB;
  auto stageB = [&](int kt, int h) {
    const bf16_t* s = gB + (size_t)(h * 128) * IN_F + kt * GK;
    bf16_t* d = Bs + ((kt & 1) << 14) + (h << 13) + (w << 9);
    GLDS(s, d);
    GLDS(s + (size_t)64 * IN_F, d + 4096);
  };

  // ---- read addressing for 32x32 frags (byte offsets; swizzled) ----
  // lane part: row (l&15)*64, R-parity (l&16)->+2048, k-offset (l>>5)*16;
  // then st_16x32 XOR (bit 5). Frag (idx,k): idx*4096 + (k>>1)*1024, with
  // the k-odd 32B XORed into the swizzled low bits (NOT added: bit-5 carry).
  const int rdx = (((l & 15) << 6) | ((l & 16) << 7) | ((l & 32) >> 1)) ^
                  ((l & 8) ? 32 : 0);
  const char* const aRd = (const char*)As + (wm << 14);
  const char* const bRd =
      (const char*)Bs + ((wn >> 1) << 14) + ((wn & 1) << 13);

#define RDA(bb, i, k)                                                     \
  (*(const bf16x8*)(aRd + ((bb) << 15) + ((i) << 12) +                    \
                    (((k) >> 1) << 10) + (rdx ^ (((k) & 1) << 5))))
#define RDB(bb, j, k)                                                     \
  (*(const bf16x8*)(bRd + ((bb) << 15) + ((j) << 12) +                    \
                    (((k) >> 1) << 10) + (rdx ^ (((k) & 1) << 5))))

  f32x16 acc[4][2];
#pragma unroll
  for (int i = 0; i < 4; ++i)
#pragma unroll
    for (int j = 0; j < 2; ++j)
#pragma unroll
      for (int r = 0; r < 16; ++r) acc[i][j][r] = 0.f;

  // fragment slots: faA = row-tiles 0,1; faB = row-tiles 2,3; fb = cols.
  // second index = kstep parity (k and k+2 share a slot; liveness checked).
  bf16x8 faA[2][2], faB[2][2], fb[2][2];

// 4-MFMA cluster: acc[2P+i2][j] += FA[i2][K&1] * fb[j][K&1]
#define CL4(P, K, FA)                                                     \
  __builtin_amdgcn_s_setprio(1);                                          \
  _Pragma("unroll") for (int i2 = 0; i2 < 2; ++i2)                        \
      _Pragma("unroll") for (int j = 0; j < 2; ++j)                       \
          acc[((P) << 1) + i2][j] =                                       \
              __builtin_amdgcn_mfma_f32_32x32x16_bf16(                    \
                  FA[i2][(K) & 1], fb[j][(K) & 1],                        \
                  acc[((P) << 1) + i2][j], 0, 0, 0);                      \
  __builtin_amdgcn_s_setprio(0);                                          \
  SB0();

  // ---- prologue: stage A(0) h0+h1, B(0) h0+h1, B(1) h0+h1; drain all
  // but B(1); barrier; pre-reads: A01 k0, B k0 (buf 0)
  stageA(0, 0); stageA(0, 1); stageB(0, 0); stageB(0, 1);
  stageB(1, 0); stageB(1, 1);
  asm volatile("s_waitcnt vmcnt(4)" ::: "memory");
  SB0();
  __builtin_amdgcn_s_barrier();
  faA[0][0] = RDA(0, 0, 0);
  faA[1][0] = RDA(0, 1, 0);
  fb[0][0] = RDB(0, 0, 0);
  fb[1][0] = RDB(0, 1, 0);
  SB0();

  for (int t = 0; t < NT; ++t) {
    const int b = t & 1;
    const int kt1 = (t + 1) & (NT - 1);   // wrap: stale tail stages, safe
    const int kt2 = (t + 2) & (NT - 1);

    // ---- s0: rd{A01 k1, B k1}; c(0,0); stageA(t+1,h0); P0 ----
    faA[0][1] = RDA(b, 0, 1);
    faA[1][1] = RDA(b, 1, 1);
    fb[0][1] = RDB(b, 0, 1);
    fb[1][1] = RDB(b, 1, 1);
    SB0();
    CL4(0, 0, faA)
    stageA(kt1, 0);
    asm volatile("s_waitcnt vmcnt(6)" ::: "memory");   // drains A(t)h1
    SB0();
    __builtin_amdgcn_s_barrier();                      // P0

    // ---- s1: rd{A23 k0}; c(0,1) ----
    faB[0][0] = RDA(b, 2, 0);
    faB[1][0] = RDA(b, 3, 0);
    SB0();
    CL4(0, 1, faA)

    // ---- s2: rd{A23 k1}; c(1,0); stageA(t+1,h1) ----
    faB[0][1] = RDA(b, 2, 1);
    faB[1][1] = RDA(b, 3, 1);
    SB0();
    CL4(1, 0, faB)
    stageA(kt1, 1);

    // ---- s3: rd{A01 k2, B k2}; c(1,1) ----
    faA[0][0] = RDA(b, 0, 2);
    faA[1][0] = RDA(b, 1, 2);
    fb[0][0] = RDB(b, 0, 2);
    fb[1][0] = RDB(b, 1, 2);
    SB0();
    CL4(1, 1, faB)

    // ---- s4: rd{A01 k3, B k3}; c(0,2) ----
    faA[0][1] = RDA(b, 0, 3);
    faA[1][1] = RDA(b, 1, 3);
    fb[0][1] = RDB(b, 0, 3);
    fb[1][1] = RDB(b, 1, 3);
    SB0();
    CL4(0, 2, faA)

    // ---- s5: rd{A23 k2}; c(0,3); P2 ----
    faB[0][0] = RDA(b, 2, 2);
    faB[1][0] = RDA(b, 3, 2);
    SB0();
    CL4(0, 3, faA)
    asm volatile("s_waitcnt vmcnt(2)" ::: "memory");   // B(t+1)+A(t+1)h0
    SB0();
    __builtin_amdgcn_s_barrier();                      // P2

    // ---- s6: rd{A23 k3}; c(1,2); stageB(t+2,h0) ----
    faB[0][1] = RDA(b, 2, 3);
    faB[1][1] = RDA(b, 3, 3);
    SB0();
    CL4(1, 2, faB)
    stageB(kt2, 0);

    // ---- s7: rd{A01 k0', B k0' (next tile)}; c(1,3); stageB(t+2,h1) ----
    faA[0][0] = RDA(b ^ 1, 0, 0);
    faA[1][0] = RDA(b ^ 1, 1, 0);
    fb[0][0] = RDB(b ^ 1, 0, 0);
    fb[1][0] = RDB(b ^ 1, 1, 0);
    SB0();
    CL4(1, 3, faB)
    stageB(kt2, 1);
  }
#undef CL4
#undef RDA
#undef RDB

  // drain in-flight GLDS before epilogue/endpgm
  asm volatile("s_waitcnt vmcnt(0)" ::: "memory");
  SB0();

  // epilogue: 32x32 C/D layout col=lane&31, row=(r&3)+8*(r>>2)+4*(lane>>5)
  const int r0 = m0 + (wm << 7) + ((l >> 5) << 2);
  const int c0 = n0 + (wn << 6) + (l & 31);
#pragma unroll
  for (int i = 0; i < 4; ++i)
#pragma unroll
    for (int j = 0; j < 2; ++j)
#pragma unroll
      for (int r = 0; r < 16; ++r) {
        const int row = r0 + (i << 5) + ((r >> 2) << 3) + (r & 3);
        C[(size_t)row * OUT_F + c0 + (j << 5)] = acc[i][j][r];
      }
}

// ------- GEMM (fallback, round-3 passing kernel): X f32, W bf16 -----------
__global__ __launch_bounds__(256) void gemm_fb(
    const float* __restrict__ X, const bf16_t* __restrict__ W,
    float* __restrict__ C) {
  __shared__ __align__(16) bf16_t Asf[BM * BK];
  __shared__ __align__(16) bf16_t Bsf[BN * BK];

  const int tid = threadIdx.x;
  const int lane = tid & 63;
  const int wid = tid >> 6;
  const int m0 = blockIdx.y * BM;
  const int n0 = blockIdx.x * BN;

  const int srow = tid >> 2;
  const int sk = (tid & 3) << 3;
  const float* ag0 = X + (size_t)(m0 + srow) * IN_F + sk;
  const float* ag1 = ag0 + (size_t)64 * IN_F;
  const bf16_t* bg0 = W + (size_t)(n0 + srow) * IN_F + sk;
  const bf16_t* bg1 = bg0 + (size_t)64 * IN_F;
  bf16_t* as0 = Asf + srow * BK + sk;
  bf16_t* as1 = as0 + 64 * BK;
  bf16_t* bs0 = Bsf + srow * BK + sk;
  bf16_t* bs1 = bs0 + 64 * BK;

  const int wmf = (wid >> 1) << 6;
  const int wnf = (wid & 1) << 6;
  const int lrf = lane & 15;
  const int quadf = lane >> 4;

  f32x4 acc[4][4] = {};

  for (int k0 = 0; k0 < IN_F; k0 += BK) {
    f32x4 xa0 = *(const f32x4*)(ag0 + k0);
    f32x4 xa1 = *(const f32x4*)(ag0 + k0 + 4);
    f32x4 xb0 = *(const f32x4*)(ag1 + k0);
    f32x4 xb1 = *(const f32x4*)(ag1 + k0 + 4);
    bf16x8 rb0 = *(const bf16x8*)(bg0 + k0);
    bf16x8 rb1 = *(const bf16x8*)(bg1 + k0);

    bf16x8 ra0, ra1;
#pragma unroll
    for (int t = 0; t < 4; ++t) {
      ra0[t] = (bf16_t)xa0[t];
      ra0[t + 4] = (bf16_t)xa1[t];
      ra1[t] = (bf16_t)xb0[t];
      ra1[t + 4] = (bf16_t)xb1[t];
    }

    __syncthreads();
    *(bf16x8*)as0 = ra0;
    *(bf16x8*)as1 = ra1;
    *(bf16x8*)bs0 = rb0;
    *(bf16x8*)bs1 = rb1;
    __syncthreads();

    bf16x8 fa[4], fbv[4];
#pragma unroll
    for (int i = 0; i < 4; ++i)
      fa[i] = *(const bf16x8*)(Asf + (wmf + i * 16 + lrf) * BK + quadf * 8);
#pragma unroll
    for (int j = 0; j < 4; ++j)
      fbv[j] = *(const bf16x8*)(Bsf + (wnf + j * 16 + lrf) * BK + quadf * 8);

#pragma unroll
    for (int i = 0; i < 4; ++i)
#pragma unroll
      for (int j = 0; j < 4; ++j)
        acc[i][j] = __builtin_amdgcn_mfma_f32_16x16x32_bf16(
            fa[i], fbv[j], acc[i][j], 0, 0, 0);
  }

#pragma unroll
  for (int i = 0; i < 4; ++i)
#pragma unroll
    for (int j = 0; j < 4; ++j)
#pragma unroll
      for (int r = 0; r < 4; ++r) {
        const int row = m0 + wmf + i * 16 + (quadf << 2) + r;
        const int col = n0 + wnf + j * 16 + lrf;
        C[(size_t)row * OUT_F + col] = acc[i][j][r];
      }
}

extern "C" void kernel_launch(void* const* d_in, const int* in_sizes, int n_in,
                              void* d_out, int out_size, void* d_ws, size_t ws_size,
                              hipStream_t stream) {
  const float* x   = (const float*)d_in[0];   // fp16 in reference -> f32 here
  const int* qw    = (const int*)d_in[1];
  const int* am1   = (const int*)d_in[2];
  const float* cd1 = (const float*)d_in[3];
  const float* of1 = (const float*)d_in[4];
  const float* am2 = (const float*)d_in[5];
  const float* cd2 = (const float*)d_in[6];
  float* out = (float*)d_out;                 // fp16 in reference -> f32 here

  const size_t W_BYTES  = (size_t)OUT_F * IN_F * 2;   // 32 MiB
  const size_t XB_BYTES = (size_t)TOKENS * IN_F * 2;  // 64 MiB
  bf16_t* W = (bf16_t*)d_ws;

  dequant_nf4<<<dim3((OUT_F * IN_F) / 8 / 256), dim3(256), 0, stream>>>(
      qw, am1, cd1, of1, am2, cd2, W);

  if (ws_size >= W_BYTES + XB_BYTES) {
    // fast path: pre-convert X to bf16, 256^2 32x32x16 decoupled GEMM
    bf16_t* Xb = (bf16_t*)((char*)d_ws + W_BYTES);
    conv_x<<<dim3((TOKENS * IN_F) / 8 / 256), dim3(256), 0, stream>>>(x, Xb);
    gemm_8p<<<dim3((TOKENS / 256) * (OUT_F / 256)), dim3(512), 0, stream>>>(
        Xb, W, out);
  } else {
    // fallback: round-3 passing kernel (f32 X converted at staging)
    dim3 grid(OUT_F / BN, TOKENS / BM);
    gemm_fb<<<grid, dim3(256), 0, stream>>>(x, W, out);
  }
}